// Round 11
// baseline (206.699 us; speedup 1.0000x reference)
//
#include <hip/hip_runtime.h>
#include <hip/hip_bf16.h>
#include <stdint.h>

#define K_DIM 4096
#define NKT   (K_DIM / 128)   // 32 K-tiles of BK=128 (i8)

typedef __attribute__((ext_vector_type(4))) float f32x4;
typedef __attribute__((ext_vector_type(4))) int i32x4;
typedef __attribute__((ext_vector_type(16))) int i32x16;

#define GLOAD_LDS16(g, l)                                                        \
  __builtin_amdgcn_global_load_lds(                                              \
      (const __attribute__((address_space(1))) void*)(g),                        \
      (__attribute__((address_space(3))) void*)(l), 16, 0, 0)

// ---------------- gamma = mean(|W|): deterministic 2-stage reduction ----------
__global__ void absum_partial(const float* __restrict__ W,
                              float* __restrict__ partials, int n) {
  int tid = blockIdx.x * blockDim.x + threadIdx.x;
  int stride = gridDim.x * blockDim.x;
  const f32x4* W4 = (const f32x4*)W;
  int n4 = n >> 2;
  float s = 0.f;
  for (int i = tid; i < n4; i += stride) {
    f32x4 v = W4[i];
    s += fabsf(v[0]) + fabsf(v[1]) + fabsf(v[2]) + fabsf(v[3]);
  }
#pragma unroll
  for (int off = 32; off > 0; off >>= 1) s += __shfl_down(s, off, 64);
  __shared__ float wsum[4];
  if ((threadIdx.x & 63) == 0) wsum[threadIdx.x >> 6] = s;
  __syncthreads();
  if (threadIdx.x == 0)
    partials[blockIdx.x] = wsum[0] + wsum[1] + wsum[2] + wsum[3];
}

__global__ void gamma_finalize(const float* __restrict__ partials,
                               float* __restrict__ gamma, float inv_n) {
  __shared__ float sm[256];
  int t = threadIdx.x;
  sm[t] = partials[t] + partials[t + 256] + partials[t + 512] + partials[t + 768];
  __syncthreads();
  for (int off = 128; off > 0; off >>= 1) {
    if (t < off) sm[t] += sm[t + off];
    __syncthreads();
  }
  if (t == 0) gamma[0] = sm[0] * inv_n;
}

// ---------------- W -> ternary i8 (exact {-1,0,1}) ----------------------------
__global__ void quantize_w_i8(const float* __restrict__ W,
                              signed char* __restrict__ Wq,
                              const float* __restrict__ gamma_p, int n) {
  float g = gamma_p[0];
  float safe = (g == 0.f) ? 1.f : g;
  int tid = blockIdx.x * blockDim.x + threadIdx.x;
  int stride = gridDim.x * blockDim.x;
  const f32x4* W4 = (const f32x4*)W;
  int n4 = n >> 2;
  int* out = (int*)Wq;
  for (int i = tid; i < n4; i += stride) {
    f32x4 v = W4[i];
    int b0, b1, b2, b3;
    float t0 = rintf(v[0] / safe);
    float t1 = rintf(v[1] / safe);
    float t2 = rintf(v[2] / safe);
    float t3 = rintf(v[3] / safe);
    b0 = (t0 >= 0.5f) ? 1 : (t0 <= -0.5f ? -1 : 0);
    b1 = (t1 >= 0.5f) ? 1 : (t1 <= -0.5f ? -1 : 0);
    b2 = (t2 >= 0.5f) ? 1 : (t2 <= -0.5f ? -1 : 0);
    b3 = (t3 >= 0.5f) ? 1 : (t3 <= -0.5f ? -1 : 0);
    out[i] = (b0 & 255) | ((b1 & 255) << 8) | ((b2 & 255) << 16) |
             ((b3 & 255) << 24);
  }
}

// -------- x fp32 -> i8 with per-row scale: x_q = rint(127*x/rowmax) -----------
__global__ __launch_bounds__(256)
void quant_x_i8(const float* __restrict__ X, signed char* __restrict__ Xq,
                float* __restrict__ xscale) {
  int row = blockIdx.x;
  int t = threadIdx.x;
  const f32x4* xr = (const f32x4*)(X + (size_t)row * K_DIM);
  f32x4 v0 = xr[t], v1 = xr[t + 256], v2 = xr[t + 512], v3 = xr[t + 768];
  float mx = 0.f;
#define AMAX4(V)                                                               \
  mx = fmaxf(mx, fmaxf(fmaxf(fabsf(V[0]), fabsf(V[1])),                        \
                       fmaxf(fabsf(V[2]), fabsf(V[3]))));
  AMAX4(v0) AMAX4(v1) AMAX4(v2) AMAX4(v3)
#undef AMAX4
#pragma unroll
  for (int off = 32; off > 0; off >>= 1) mx = fmaxf(mx, __shfl_down(mx, off, 64));
  __shared__ float wmx[4];
  if ((t & 63) == 0) wmx[t >> 6] = mx;
  __syncthreads();
  float rmax = fmaxf(fmaxf(wmx[0], wmx[1]), fmaxf(wmx[2], wmx[3]));
  float inv = (rmax > 0.f) ? 127.0f / rmax : 0.f;
  if (t == 0) xscale[row] = (rmax > 0.f) ? rmax / 127.0f : 0.f;
  int* out = (int*)(Xq + (size_t)row * K_DIM);
#define PACK(V, IDX)                                                           \
  {                                                                            \
    int c0 = __float2int_rn(V[0] * inv), c1 = __float2int_rn(V[1] * inv);      \
    int c2 = __float2int_rn(V[2] * inv), c3 = __float2int_rn(V[3] * inv);      \
    out[IDX] = (c0 & 255) | ((c1 & 255) << 8) | ((c2 & 255) << 16) |           \
               ((c3 & 255) << 24);                                             \
  }
  PACK(v0, t) PACK(v1, t + 256) PACK(v2, t + 512) PACK(v3, t + 768)
#undef PACK
}

// ---- 256x256 i8 GEMM: 32x32x32 MFMA with R9's consumption order (race-free) --
// out[r][c] = gamma * xscale[r] * sum_k Wq[c][k] * Xq[r][k]  (exact i32 dot)
// 512 thr = 8 waves (2Mx4N), wave out 128x64 = 4 m-frags x 2 n-frags of
// mfma_i32_32x32x32_i8 (acc 16 i32/frag = 128 regs). K-tile BK=128 = 2
// ks-halves x 2 k-steps of 32. LDS physical layout & stage stream VERBATIM R9
// (3x passed): per matrix [2 buf][2 half][256 rows][64 B] = 64KB, A+B 128KiB.
// Phase = (H, MH): MH==0 reads B-half-H (2 nfrag x 2 kstep, held in regs
// through MH==1) + A(MH,H); MH==1 reads only A. -> LDS last-read map is
// EXACTLY R9's {B-h0:ph0, A-h0:ph1, B-h1:ph2, A-h1:ph3}, so the R9 stage
// stream {ph0: A-h1(kt+1)->buf^1; ph1: B-h0(kt+2); ph2: A-h0(kt+2);
// ph3: B-h1(kt+2)+vmcnt(6)} is WAR-safe by the proven ledger. R10's failure
// was breaking this map while keeping the stream (race), not the frag layout.
// A/B frag map (32x32x32, contiguous like verified 16x16x64): lane l -> row
// l&31, k-bytes (l>>5)*16+j within the 32B k-step; chunk-in-half clog =
// kstep*2 + (l>>5); swizzle cphys = clog ^ ((l>>1)&3) folded into 2 bases.
// Bank audit: 32 rows x 2 chunks -> 8 dwords/bank/wave = conflict-free.
// C/D map (m74/m101, dtype-indep): col=lane&31, row=(reg&3)+8*(reg>>2)+4*hi.
__global__ __launch_bounds__(512, 2)
void gemm_i8_32(const signed char* __restrict__ A,
                const signed char* __restrict__ Bq,
                float* __restrict__ C,
                const float* __restrict__ gamma_p,
                const float* __restrict__ xscale, int M, int N) {
  __shared__ __align__(16) signed char Ab[2][2][256][64];  // 64 KiB
  __shared__ __align__(16) signed char Bb[2][2][256][64];  // 64 KiB

  int ntN = N >> 8;
  int bid = blockIdx.x;
  int swz = (bid & 7) * (gridDim.x >> 3) + (bid >> 3);  // nwg % 8 == 0
  int tm = swz / ntN, tn = swz % ntN;

  int t = threadIdx.x;
  int lane = t & 63;
  int wid = t >> 6;
  int wr = wid >> 2, wc = wid & 3;   // 2 x 4 wave grid, wave out 128x64
  int l31 = lane & 31;
  int hi = lane >> 5;                // 16B sub-chunk within 32B k-step
  int x21 = (lane >> 1) & 3;         // swizzle XOR (== fragment row bits[2:1])

  const signed char* aG = A + (size_t)tm * 256 * K_DIM;
  const signed char* bG = Bq + (size_t)tn * 256 * K_DIM;

  // staging (verbatim R9): thread t -> LDS row t>>2 (+128), phys chunk t&3;
  // global source chunk = (t&3) ^ ((t>>3)&3)
  int srow = t >> 2;
  int sclog = (t & 3) ^ ((t >> 3) & 3);
  const signed char* aSg = aG + (size_t)srow * K_DIM + (sclog << 4);
  const signed char* bSg = bG + (size_t)srow * K_DIM + (sclog << 4);
  char* aSl = (char*)Ab + t * 16;
  char* bSl = (char*)Bb + t * 16;

  // read bases: kstep s=0 -> chunk (hi^x21); s=1 -> ((2|hi)^x21)
  const signed char* aRdB = &Ab[0][0][0][0] + (wr * 128 + l31) * 64;
  const signed char* bRdB = &Bb[0][0][0][0] + (wc * 64 + l31) * 64;
  const signed char* aRd0 = aRdB + ((hi ^ x21) << 4);
  const signed char* aRd1 = aRdB + (((2 | hi) ^ x21) << 4);
  const signed char* bRd0 = bRdB + ((hi ^ x21) << 4);
  const signed char* bRd1 = bRdB + (((2 | hi) ^ x21) << 4);

  i32x16 acc[4][2];
#pragma unroll
  for (int m = 0; m < 4; ++m)
#pragma unroll
    for (int n = 0; n < 2; ++n) acc[m][n] = (i32x16)(0);

#define STAGE_A(J, BUF, KS)                                                    \
  { GLOAD_LDS16(aSg + (size_t)(J) * 128 + (KS) * 64,                           \
                aSl + (BUF) * 32768 + (KS) * 16384);                           \
    GLOAD_LDS16(aSg + (size_t)(J) * 128 + (KS) * 64 + (size_t)128 * K_DIM,     \
                aSl + (BUF) * 32768 + (KS) * 16384 + 8192); }
#define STAGE_B(J, BUF, KS)                                                    \
  { GLOAD_LDS16(bSg + (size_t)(J) * 128 + (KS) * 64,                           \
                bSl + (BUF) * 32768 + (KS) * 16384);                           \
    GLOAD_LDS16(bSg + (size_t)(J) * 128 + (KS) * 64 + (size_t)128 * K_DIM,     \
                bSl + (BUF) * 32768 + (KS) * 16384 + 8192); }
#define BAR() __builtin_amdgcn_s_barrier()
#define VMC(NN) asm volatile("s_waitcnt vmcnt(" #NN ")" ::: "memory")
#define LGKM0() asm volatile("s_waitcnt lgkmcnt(0)" ::: "memory")
#define SB0() __builtin_amdgcn_sched_barrier(0)

  // PHASE(H: ks-half 0|1, MH: m-half 0|1, BUF, STG, VEND)
  // MH==0: read B-half-H (4 b128, persists through MH==1) + A (4 b128)
  // MH==1: read A only (4 b128); B reused from registers.
#define PHASE(H, MH, BUF, STG, VEND)                                           \
  {                                                                            \
    if ((MH) == 0) {                                                           \
      _Pragma("unroll") for (int n = 0; n < 2; ++n) {                          \
        bf[n][0] = *(const i32x4*)(bRd0 + (BUF) * 32768 + (H) * 16384 +        \
                                   n * 2048);                                  \
        bf[n][1] = *(const i32x4*)(bRd1 + (BUF) * 32768 + (H) * 16384 +        \
                                   n * 2048);                                  \
      }                                                                        \
    }                                                                          \
    _Pragma("unroll") for (int m = 0; m < 2; ++m) {                            \
      af[m][0] = *(const i32x4*)(aRd0 + (BUF) * 32768 + (H) * 16384 +          \
                                 (MH) * 4096 + m * 2048);                      \
      af[m][1] = *(const i32x4*)(aRd1 + (BUF) * 32768 + (H) * 16384 +          \
                                 (MH) * 4096 + m * 2048);                      \
    }                                                                          \
    STG;                                                                       \
    BAR(); LGKM0(); SB0();                                                     \
    __builtin_amdgcn_s_setprio(1);                                             \
    _Pragma("unroll") for (int s = 0; s < 2; ++s)                              \
      _Pragma("unroll") for (int m = 0; m < 2; ++m)                            \
        _Pragma("unroll") for (int n = 0; n < 2; ++n)                          \
          acc[(MH) * 2 + m][n] = __builtin_amdgcn_mfma_i32_32x32x32_i8(        \
              af[m][s], bf[n][s], acc[(MH) * 2 + m][n], 0, 0, 0);              \
    __builtin_amdgcn_s_setprio(0);                                             \
    VEND;                                                                      \
    BAR();                                                                     \
  }

  // TILE: stage stream verbatim R9
#define TILE(KT, BUF, DO_S1, DO_S2, VEND)                                      \
  {                                                                            \
    PHASE(0, 0, BUF, if (DO_S1) STAGE_A((KT) + 1, (BUF) ^ 1, 1), (void)0);     \
    PHASE(0, 1, BUF, if (DO_S2) STAGE_B((KT) + 2, BUF, 0), (void)0);           \
    PHASE(1, 0, BUF, if (DO_S2) STAGE_A((KT) + 2, BUF, 0), (void)0);           \
    PHASE(1, 1, BUF, if (DO_S2) STAGE_B((KT) + 2, BUF, 1), VEND; SB0());       \
  }

  // prologue (verbatim R9): tile0 all 4 halves + tile1 {B-h0, A-h0, B-h1};
  // vmcnt(6): tile0's 8 complete, tile1's 6 in flight
  STAGE_B(0, 0, 0); STAGE_A(0, 0, 0); STAGE_B(0, 0, 1); STAGE_A(0, 0, 1);
  STAGE_B(1, 1, 0); STAGE_A(1, 1, 0); STAGE_B(1, 1, 1);
  VMC(6); SB0();
  BAR();

  i32x4 af[2][2], bf[2][2];
  for (int i = 0; i < 15; ++i) {
    int kt = i << 1;
    TILE(kt, 0, 1, 1, VMC(6));
    TILE(kt + 1, 1, 1, 1, VMC(6));
  }
  // tile 30: stage A-h1(31) only; drain everything
  TILE(30, 0, 1, 0, VMC(0));
  // tile 31: no stages, no vmcnt
  TILE(31, 1, 0, 0, (void)0);

  float g = gamma_p[0];
  size_t row0 = (size_t)tm * 256 + wr * 128 + 4 * hi;
  int col0 = tn * 256 + wc * 64 + l31;
#pragma unroll
  for (int m = 0; m < 4; ++m) {
#pragma unroll
    for (int j = 0; j < 16; ++j) {
      size_t row = row0 + m * 32 + (j & 3) + 8 * (j >> 2);
      float sc = g * xscale[row];
      float* cp = C + row * (size_t)N + col0;
#pragma unroll
      for (int n = 0; n < 2; ++n) cp[n * 32] = (float)acc[m][n][j] * sc;
    }
  }
#undef STAGE_A
#undef STAGE_B
#undef BAR
#undef VMC
#undef LGKM0
#undef SB0
#undef PHASE
#undef TILE
}

// ---------------- naive fallback (only if ws too small / odd shapes) ----------
__global__ void naive_bitlinear(const float* __restrict__ X,
                                const float* __restrict__ W,
                                float* __restrict__ out,
                                const float* __restrict__ gamma_p, int M, int N) {
  int col = blockIdx.x * blockDim.x + threadIdx.x;
  int row = blockIdx.y;
  if (col >= N || row >= M) return;
  float g = gamma_p[0];
  float safe = (g == 0.f) ? 1.f : g;
  const float* x = X + (size_t)row * K_DIM;
  const float* w = W + (size_t)col * K_DIM;
  float s = 0.f;
  for (int k = 0; k < K_DIM; ++k) {
    float qv = fminf(fmaxf(rintf(w[k] / safe), -1.f), 1.f);
    s += x[k] * qv;
  }
  out[(size_t)row * N + col] = s * g;
}

extern "C" void kernel_launch(void* const* d_in, const int* in_sizes, int n_in,
                              void* d_out, int out_size, void* d_ws,
                              size_t ws_size, hipStream_t stream) {
  const float* x = (const float*)d_in[0];
  const float* w = (const float*)d_in[1];
  float* out = (float*)d_out;
  int xn = in_sizes[0];   // B*S*D_IN = 33554432
  int wn = in_sizes[1];   // D_OUT*D_IN = 16777216
  int M = xn / K_DIM;     // 8192
  int N = wn / K_DIM;     // 4096

  char* ws = (char*)d_ws;
  float* partials = (float*)ws;                        // 1024 floats
  float* gamma = (float*)(ws + 4096);                  // 1 float
  float* xscale = (float*)(ws + 8192);                 // M floats (32 KiB)
  signed char* Wq = (signed char*)(ws + 8192 + 32768); // N*K i8
  signed char* Xq = Wq + (size_t)wn;                   // M*K i8
  size_t need = 8192 + 32768 + (size_t)wn + (size_t)xn;

  absum_partial<<<1024, 256, 0, stream>>>(w, partials, wn);
  gamma_finalize<<<1, 256, 0, stream>>>(partials, gamma, 1.0f / (float)wn);

  if (ws_size >= need && (M & 255) == 0 && (N & 255) == 0) {
    quantize_w_i8<<<2048, 256, 0, stream>>>(w, Wq, gamma, wn);
    quant_x_i8<<<M, 256, 0, stream>>>(x, Xq, xscale);
    int nwg = (M >> 8) * (N >> 8);   // 32 * 16 = 512
    gemm_i8_32<<<nwg, 512, 0, stream>>>(Xq, Wq, out, gamma, xscale, M, N);
  } else {
    dim3 grid((N + 255) / 256, M);
    naive_bitlinear<<<grid, 256, 0, stream>>>(x, w, out, gamma, M, N);
  }
}